// Round 1
// baseline (673.420 us; speedup 1.0000x reference)
//
#include <hip/hip_runtime.h>
#include <cmath>

#define LRELU(e) ((e) > 0.f ? (e) : 0.2f*(e))

// ---------------- CSR build ----------------
__global__ void k_hist(const int* __restrict__ dst, int* __restrict__ deg, int E) {
  int e = blockIdx.x*blockDim.x + threadIdx.x;
  if (e < E) atomicAdd(&deg[dst[e]], 1);
}

__global__ __launch_bounds__(1024) void k_scan1(const int* __restrict__ deg,
                        int* __restrict__ row_start, int* __restrict__ bsums, int n) {
  __shared__ int sm[1024];
  int t = threadIdx.x;
  int i = blockIdx.x*1024 + t;
  sm[t] = (i < n) ? deg[i] : 0;
  __syncthreads();
  for (int off = 1; off < 1024; off <<= 1) {
    int v = (t >= off) ? sm[t-off] : 0;
    __syncthreads();
    sm[t] += v;
    __syncthreads();
  }
  if (i < n) row_start[i+1] = sm[t];
  if (t == 1023) bsums[blockIdx.x] = sm[1023];
  if (i == 0) row_start[0] = 0;
}

__global__ void k_scan2(int* __restrict__ bsums, int nb) {
  __shared__ int sm[64];
  int t = threadIdx.x;
  sm[t] = (t < nb) ? bsums[t] : 0;
  __syncthreads();
  for (int off = 1; off < 64; off <<= 1) {
    int v = (t >= off) ? sm[t-off] : 0;
    __syncthreads();
    sm[t] += v;
    __syncthreads();
  }
  if (t < nb) bsums[t] = (t == 0) ? 0 : sm[t-1];
}

__global__ __launch_bounds__(1024) void k_scan3(int* __restrict__ row_start,
                        const int* __restrict__ bsums, int n) {
  int i = blockIdx.x*1024 + threadIdx.x;
  if (i < n) row_start[i+1] += bsums[blockIdx.x];
}

__global__ void k_fill(const int* __restrict__ src, const int* __restrict__ dst,
                       const int* __restrict__ row_start, int* __restrict__ cursor,
                       int* __restrict__ csr_src, int E) {
  int e = blockIdx.x*blockDim.x + threadIdx.x;
  if (e < E) {
    int d = dst[e];
    int pos = atomicAdd(&cursor[d], 1);
    csr_src[row_start[d] + pos] = src[e];
  }
}

// ---------------- GEMM1: feat1[N,256] = x[N,512] @ W1[512,256] ----------------
// BM=64, BN=256 (full N), BK=8, 256 threads, 8x8 per thread
__global__ __launch_bounds__(256) void k_gemm1(const float* __restrict__ x,
                        const float* __restrict__ W, float* __restrict__ out, int M) {
  const int K = 512, Nn = 256;
  __shared__ float As[8][68];    // [k][m], padded
  __shared__ float Bs[8][256];   // [k][n]
  int tid = threadIdx.x;
  int bm = blockIdx.x * 64;
  int tx = tid & 31, ty = tid >> 5;       // n0 = tx*8, m0 = ty*8
  int arow = tid >> 2;                    // 0..63
  int acol = (tid & 3) * 2;               // 0,2,4,6
  int brow = tid >> 5;                    // 0..7
  int bcol = (tid & 31) * 8;              // 0..248
  float acc[8][8] = {};
  for (int k0 = 0; k0 < K; k0 += 8) {
    float2 av = make_float2(0.f, 0.f);
    if (bm + arow < M) av = *(const float2*)(x + (size_t)(bm+arow)*K + k0 + acol);
    As[acol][arow]   = av.x;
    As[acol+1][arow] = av.y;
    float4 b0 = *(const float4*)(W + (size_t)(k0+brow)*Nn + bcol);
    float4 b1 = *(const float4*)(W + (size_t)(k0+brow)*Nn + bcol + 4);
    *(float4*)&Bs[brow][bcol]   = b0;
    *(float4*)&Bs[brow][bcol+4] = b1;
    __syncthreads();
    #pragma unroll
    for (int k = 0; k < 8; ++k) {
      float a[8], b[8];
      #pragma unroll
      for (int i = 0; i < 8; ++i) a[i] = As[k][ty*8+i];
      #pragma unroll
      for (int j = 0; j < 8; ++j) b[j] = Bs[k][tx*8+j];
      #pragma unroll
      for (int i = 0; i < 8; ++i)
        #pragma unroll
        for (int j = 0; j < 8; ++j)
          acc[i][j] = fmaf(a[i], b[j], acc[i][j]);
    }
    __syncthreads();
  }
  #pragma unroll
  for (int i = 0; i < 8; ++i) {
    int m = bm + ty*8 + i;
    if (m < M) {
      #pragma unroll
      for (int j = 0; j < 8; j += 4)
        *(float4*)(out + (size_t)m*Nn + tx*8 + j) =
            make_float4(acc[i][j], acc[i][j+1], acc[i][j+2], acc[i][j+3]);
    }
  }
}

// ---------------- GEMM2: feat2[N,64] = h1[N,256] @ W2[256,64] ----------------
// BM=64, BN=64, BK=16, 256 threads, 4x4 per thread
__global__ __launch_bounds__(256) void k_gemm2(const float* __restrict__ h1,
                        const float* __restrict__ W, float* __restrict__ out, int M) {
  const int K = 256, Nn = 64;
  __shared__ float As[16][68];
  __shared__ float Bs[16][64];
  int tid = threadIdx.x;
  int bm = blockIdx.x * 64;
  int tx = tid & 15, ty = tid >> 4;   // n0 = tx*4, m0 = ty*4
  int arow = tid >> 2;                // 0..63
  int acol = (tid & 3) * 4;           // 0,4,8,12
  int brow = tid >> 4;                // 0..15
  int bcol = (tid & 15) * 4;          // 0..60
  float acc[4][4] = {};
  for (int k0 = 0; k0 < K; k0 += 16) {
    float4 av = make_float4(0.f,0.f,0.f,0.f);
    if (bm + arow < M) av = *(const float4*)(h1 + (size_t)(bm+arow)*K + k0 + acol);
    As[acol][arow] = av.x; As[acol+1][arow] = av.y;
    As[acol+2][arow] = av.z; As[acol+3][arow] = av.w;
    *(float4*)&Bs[brow][bcol] = *(const float4*)(W + (size_t)(k0+brow)*Nn + bcol);
    __syncthreads();
    #pragma unroll
    for (int k = 0; k < 16; ++k) {
      float a[4], b[4];
      #pragma unroll
      for (int i = 0; i < 4; ++i) a[i] = As[k][ty*4+i];
      #pragma unroll
      for (int j = 0; j < 4; ++j) b[j] = Bs[k][tx*4+j];
      #pragma unroll
      for (int i = 0; i < 4; ++i)
        #pragma unroll
        for (int j = 0; j < 4; ++j)
          acc[i][j] = fmaf(a[i], b[j], acc[i][j]);
    }
    __syncthreads();
  }
  #pragma unroll
  for (int i = 0; i < 4; ++i) {
    int m = bm + ty*4 + i;
    if (m < M)
      *(float4*)(out + (size_t)m*Nn + tx*4) =
          make_float4(acc[i][0], acc[i][1], acc[i][2], acc[i][3]);
  }
}

// ---------------- attention logits: el/er (layer 1, 4 heads) ----------------
__global__ void k_lr1(const float* __restrict__ feat1, const float* __restrict__ al,
                      const float* __restrict__ ar, float* __restrict__ el,
                      float* __restrict__ er, int Nn) {
  int n = blockIdx.x;
  int t = threadIdx.x;          // = h*64 + d
  int h = t >> 6, lane = t & 63;
  float f = feat1[(size_t)n*256 + t];
  float pl = f * al[t];
  float pr = f * ar[t];
  #pragma unroll
  for (int m = 32; m >= 1; m >>= 1) {
    pl += __shfl_xor(pl, m);
    pr += __shfl_xor(pr, m);
  }
  if (lane == 0) {
    el[n*4 + h] = pl;
    er[n*4 + h] = pr;
  }
}

// ---------------- attention logits layer 2 (1 head): wave per node ----------------
__global__ void k_lr2(const float* __restrict__ feat2, const float* __restrict__ al,
                      const float* __restrict__ ar, float* __restrict__ el,
                      float* __restrict__ er, int Nn) {
  int v = blockIdx.x*4 + (threadIdx.x >> 6);
  int lane = threadIdx.x & 63;
  if (v >= Nn) return;
  float f = feat2[(size_t)v*64 + lane];
  float pl = f * al[lane];
  float pr = f * ar[lane];
  #pragma unroll
  for (int m = 32; m >= 1; m >>= 1) {
    pl += __shfl_xor(pl, m);
    pr += __shfl_xor(pr, m);
  }
  if (lane == 0) { el[v] = pl; er[v] = pr; }
}

// ---------------- layer-1 softmax + aggregate + bias + ELU -> h1 ----------------
// 1 block per dst node; wave h handles head h.
__global__ __launch_bounds__(256) void k_agg1(const float* __restrict__ feat1,
                      const float* __restrict__ el, const float* __restrict__ er,
                      const int* __restrict__ row_start, const int* __restrict__ csr_src,
                      const float* __restrict__ b1, float* __restrict__ h1, int Nn) {
  int v = blockIdx.x;
  int h = threadIdx.x >> 6, lane = threadIdx.x & 63;
  int r0 = row_start[v], r1 = row_start[v+1];
  int deg = r1 - r0;
  float erv = er[v*4 + h];
  float mx = -INFINITY;
  for (int i = lane; i < deg; i += 64) {
    int s = csr_src[r0+i];
    float e = el[s*4 + h] + erv;
    e = LRELU(e);
    mx = fmaxf(mx, e);
  }
  #pragma unroll
  for (int m = 32; m >= 1; m >>= 1) mx = fmaxf(mx, __shfl_xor(mx, m));
  float sm = 0.f;
  for (int i = lane; i < deg; i += 64) {
    int s = csr_src[r0+i];
    float e = el[s*4 + h] + erv;
    e = LRELU(e);
    sm += expf(e - mx);
  }
  #pragma unroll
  for (int m = 32; m >= 1; m >>= 1) sm += __shfl_xor(sm, m);
  float inv = (deg > 0) ? 1.f/sm : 0.f;
  float acc = 0.f;
  for (int i = 0; i < deg; ++i) {
    int s = csr_src[r0+i];
    float e = el[s*4 + h] + erv;
    e = LRELU(e);
    float w = expf(e - mx) * inv;
    acc = fmaf(feat1[(size_t)s*256 + h*64 + lane], w, acc);
  }
  float val = acc + b1[h*64 + lane];
  val = val > 0.f ? val : expm1f(val);
  h1[(size_t)v*256 + h*64 + lane] = val;
}

// ---------------- layer-2 softmax + aggregate + bias -> out ----------------
// wave per node (H=1, D=64)
__global__ __launch_bounds__(256) void k_agg2(const float* __restrict__ feat2,
                      const float* __restrict__ el, const float* __restrict__ er,
                      const int* __restrict__ row_start, const int* __restrict__ csr_src,
                      const float* __restrict__ b2, float* __restrict__ out, int Nn) {
  int v = blockIdx.x*4 + (threadIdx.x >> 6);
  int lane = threadIdx.x & 63;
  if (v >= Nn) return;
  int r0 = row_start[v], r1 = row_start[v+1];
  int deg = r1 - r0;
  float erv = er[v];
  float mx = -INFINITY;
  for (int i = lane; i < deg; i += 64) {
    int s = csr_src[r0+i];
    float e = el[s] + erv;
    e = LRELU(e);
    mx = fmaxf(mx, e);
  }
  #pragma unroll
  for (int m = 32; m >= 1; m >>= 1) mx = fmaxf(mx, __shfl_xor(mx, m));
  float sm = 0.f;
  for (int i = lane; i < deg; i += 64) {
    int s = csr_src[r0+i];
    float e = el[s] + erv;
    e = LRELU(e);
    sm += expf(e - mx);
  }
  #pragma unroll
  for (int m = 32; m >= 1; m >>= 1) sm += __shfl_xor(sm, m);
  float inv = (deg > 0) ? 1.f/sm : 0.f;
  float acc = 0.f;
  for (int i = 0; i < deg; ++i) {
    int s = csr_src[r0+i];
    float e = el[s] + erv;
    e = LRELU(e);
    float w = expf(e - mx) * inv;
    acc = fmaf(feat2[(size_t)s*64 + lane], w, acc);
  }
  out[(size_t)v*64 + lane] = acc + b2[lane];
}

extern "C" void kernel_launch(void* const* d_in, const int* in_sizes, int n_in,
                              void* d_out, int out_size, void* d_ws, size_t ws_size,
                              hipStream_t stream) {
  const float* x   = (const float*)d_in[0];
  const int*   src = (const int*)d_in[1];
  const int*   dst = (const int*)d_in[2];
  const float* W1  = (const float*)d_in[3];
  const float* al1 = (const float*)d_in[4];
  const float* ar1 = (const float*)d_in[5];
  const float* b1  = (const float*)d_in[6];
  const float* W2  = (const float*)d_in[7];
  const float* al2 = (const float*)d_in[8];
  const float* ar2 = (const float*)d_in[9];
  const float* b2  = (const float*)d_in[10];
  float* out = (float*)d_out;

  const int N = in_sizes[0] / 512;
  const int E = in_sizes[1];

  char* p = (char*)d_ws;
  auto alloc = [&](size_t bytes) {
    char* r = p; p += (bytes + 255) & ~(size_t)255; return r;
  };
  float* feat1    = (float*)alloc((size_t)N*256*sizeof(float));
  float* h1       = (float*)alloc((size_t)N*256*sizeof(float));
  float* feat2    = (float*)alloc((size_t)N*64*sizeof(float));
  float* el1      = (float*)alloc((size_t)N*4*sizeof(float));
  float* er1      = (float*)alloc((size_t)N*4*sizeof(float));
  float* el2      = (float*)alloc((size_t)N*sizeof(float));
  float* er2      = (float*)alloc((size_t)N*sizeof(float));
  int*   deg      = (int*)alloc((size_t)N*sizeof(int));
  int*   row_start= (int*)alloc((size_t)(N+1)*sizeof(int));
  int*   cursor   = (int*)alloc((size_t)N*sizeof(int));
  int*   bsums    = (int*)alloc(64*sizeof(int));
  int*   csr_src  = (int*)alloc((size_t)E*sizeof(int));

  hipMemsetAsync(deg, 0, (size_t)N*sizeof(int), stream);
  hipMemsetAsync(cursor, 0, (size_t)N*sizeof(int), stream);

  k_hist<<<(E+255)/256, 256, 0, stream>>>(dst, deg, E);
  int nb = (N + 1023)/1024;
  k_scan1<<<nb, 1024, 0, stream>>>(deg, row_start, bsums, N);
  k_scan2<<<1, 64, 0, stream>>>(bsums, nb);
  k_scan3<<<nb, 1024, 0, stream>>>(row_start, bsums, N);
  k_fill<<<(E+255)/256, 256, 0, stream>>>(src, dst, row_start, cursor, csr_src, E);

  k_gemm1<<<(N+63)/64, 256, 0, stream>>>(x, W1, feat1, N);
  k_lr1<<<N, 256, 0, stream>>>(feat1, al1, ar1, el1, er1, N);
  k_agg1<<<N, 256, 0, stream>>>(feat1, el1, er1, row_start, csr_src, b1, h1, N);
  k_gemm2<<<(N+63)/64, 256, 0, stream>>>(h1, W2, feat2, N);
  k_lr2<<<(N+3)/4, 256, 0, stream>>>(feat2, al2, ar2, el2, er2, N);
  k_agg2<<<(N+3)/4, 256, 0, stream>>>(feat2, el2, er2, row_start, csr_src, b2, out, N);
}

// Round 3
// 410.743 us; speedup vs baseline: 1.6395x; 1.6395x over previous
//
#include <hip/hip_runtime.h>
#include <cmath>

#define LRELU(e) ((e) > 0.f ? (e) : 0.2f*(e))

typedef __bf16 bf16x8 __attribute__((ext_vector_type(8)));
typedef float  f32x4  __attribute__((ext_vector_type(4)));

// ---------------- CSR build ----------------
__global__ void k_hist(const int* __restrict__ dst, int* __restrict__ deg, int E) {
  int e = blockIdx.x*blockDim.x + threadIdx.x;
  if (e < E) atomicAdd(&deg[dst[e]], 1);
}

__global__ __launch_bounds__(1024) void k_scan1(const int* __restrict__ deg,
                        int* __restrict__ row_start, int* __restrict__ bsums, int n) {
  __shared__ int sm[1024];
  int t = threadIdx.x;
  int i = blockIdx.x*1024 + t;
  sm[t] = (i < n) ? deg[i] : 0;
  __syncthreads();
  for (int off = 1; off < 1024; off <<= 1) {
    int v = (t >= off) ? sm[t-off] : 0;
    __syncthreads();
    sm[t] += v;
    __syncthreads();
  }
  if (i < n) row_start[i+1] = sm[t];
  if (t == 1023) bsums[blockIdx.x] = sm[1023];
  if (i == 0) row_start[0] = 0;
}

__global__ void k_scan2(int* __restrict__ bsums, int nb) {
  __shared__ int sm[64];
  int t = threadIdx.x;
  sm[t] = (t < nb) ? bsums[t] : 0;
  __syncthreads();
  for (int off = 1; off < 64; off <<= 1) {
    int v = (t >= off) ? sm[t-off] : 0;
    __syncthreads();
    sm[t] += v;
    __syncthreads();
  }
  if (t < nb) bsums[t] = (t == 0) ? 0 : sm[t-1];
}

__global__ __launch_bounds__(1024) void k_scan3(int* __restrict__ row_start,
                        const int* __restrict__ bsums, int n) {
  int i = blockIdx.x*1024 + threadIdx.x;
  if (i < n) row_start[i+1] += bsums[blockIdx.x];
}

__global__ void k_fill(const int* __restrict__ src, const int* __restrict__ dst,
                       const int* __restrict__ row_start, int* __restrict__ cursor,
                       int* __restrict__ csr_src, int E) {
  int e = blockIdx.x*blockDim.x + threadIdx.x;
  if (e < E) {
    int d = dst[e];
    int pos = atomicAdd(&cursor[d], 1);
    csr_src[row_start[d] + pos] = src[e];
  }
}

// ---------------- W1 transpose + bf16 convert: W1T[256][512] ----------------
__global__ void k_w1t(const float* __restrict__ W1, __bf16* __restrict__ W1T) {
  int idx = blockIdx.x*blockDim.x + threadIdx.x;   // n*512 + k
  if (idx < 256*512) {
    int n = idx >> 9, k = idx & 511;
    W1T[idx] = (__bf16)W1[k*256 + n];
  }
}

// ---------------- GEMM1 (bf16 MFMA): feat1[N,256] = x[N,512] @ W1[512,256] ----
// BM=128, BN=128, BK=32. 256 threads = 4 waves (2x2), wave tile 64x64.
__global__ __launch_bounds__(256) void k_gemm1(const float* __restrict__ x,
                        const __bf16* __restrict__ W1T, float* __restrict__ out, int M) {
  const int K = 512, Nn = 256;
  __shared__ __bf16 A_sm[128][40];   // [m][k], pad to 40 (80B stride)
  __shared__ __bf16 B_sm[128][40];   // [n][k]
  int tid = threadIdx.x;
  int lane = tid & 63, wid = tid >> 6;
  int wm = wid >> 1, wn = wid & 1;           // 2x2 waves
  int bm = blockIdx.x * 128;
  int bn = blockIdx.y * 128;

  int srow = tid >> 2;            // 0..63
  int scol = (tid & 3) * 8;       // 0,8,16,24

  f32x4 acc[4][4];
  #pragma unroll
  for (int i = 0; i < 4; ++i)
    #pragma unroll
    for (int j = 0; j < 4; ++j) acc[i][j] = (f32x4){0.f,0.f,0.f,0.f};

  for (int k0 = 0; k0 < K; k0 += 32) {
    // stage A: x[bm+row][k0+col] f32 -> bf16
    #pragma unroll
    for (int p = 0; p < 2; ++p) {
      int row = srow + p*64;
      bf16x8 v;
      if (bm + row < M) {
        const float* xp = x + (size_t)(bm+row)*K + k0 + scol;
        float4 f0 = *(const float4*)xp;
        float4 f1 = *(const float4*)(xp+4);
        v[0]=(__bf16)f0.x; v[1]=(__bf16)f0.y; v[2]=(__bf16)f0.z; v[3]=(__bf16)f0.w;
        v[4]=(__bf16)f1.x; v[5]=(__bf16)f1.y; v[6]=(__bf16)f1.z; v[7]=(__bf16)f1.w;
      } else {
        v = (bf16x8){};
      }
      *(bf16x8*)&A_sm[row][scol] = v;
      // stage B: W1T[bn+row][k0+col] bf16 copy
      *(bf16x8*)&B_sm[row][scol] = *(const bf16x8*)(W1T + (size_t)(bn+row)*K + k0 + scol);
    }
    __syncthreads();
    #pragma unroll
    for (int mf = 0; mf < 4; ++mf) {
      bf16x8 a = *(const bf16x8*)&A_sm[wm*64 + mf*16 + (lane&15)][(lane>>4)*8];
      #pragma unroll
      for (int nf = 0; nf < 4; ++nf) {
        bf16x8 b = *(const bf16x8*)&B_sm[wn*64 + nf*16 + (lane&15)][(lane>>4)*8];
        acc[mf][nf] = __builtin_amdgcn_mfma_f32_16x16x32_bf16(a, b, acc[mf][nf], 0, 0, 0);
      }
    }
    __syncthreads();
  }
  // epilogue: C row = (lane>>4)*4 + j, col = lane&15 within each 16x16 frag
  #pragma unroll
  for (int mf = 0; mf < 4; ++mf) {
    #pragma unroll
    for (int j = 0; j < 4; ++j) {
      int m = bm + wm*64 + mf*16 + (lane>>4)*4 + j;
      if (m < M) {
        #pragma unroll
        for (int nf = 0; nf < 4; ++nf) {
          int n = bn + wn*64 + nf*16 + (lane&15);
          out[(size_t)m*Nn + n] = acc[mf][nf][j];
        }
      }
    }
  }
}

// ---------------- GEMM2: feat2[N,64] = h1[N,256] @ W2[256,64] (f32) ----------
__global__ __launch_bounds__(256) void k_gemm2(const float* __restrict__ h1,
                        const float* __restrict__ W, float* __restrict__ out, int M) {
  const int K = 256, Nn = 64;
  __shared__ float As[16][68];
  __shared__ float Bs[16][64];
  int tid = threadIdx.x;
  int bm = blockIdx.x * 64;
  int tx = tid & 15, ty = tid >> 4;
  int arow = tid >> 2;
  int acol = (tid & 3) * 4;
  int brow = tid >> 4;
  int bcol = (tid & 15) * 4;
  float acc[4][4] = {};
  for (int k0 = 0; k0 < K; k0 += 16) {
    float4 av = make_float4(0.f,0.f,0.f,0.f);
    if (bm + arow < M) av = *(const float4*)(h1 + (size_t)(bm+arow)*K + k0 + acol);
    As[acol][arow] = av.x; As[acol+1][arow] = av.y;
    As[acol+2][arow] = av.z; As[acol+3][arow] = av.w;
    *(float4*)&Bs[brow][bcol] = *(const float4*)(W + (size_t)(k0+brow)*Nn + bcol);
    __syncthreads();
    #pragma unroll
    for (int k = 0; k < 16; ++k) {
      float a[4], b[4];
      #pragma unroll
      for (int i = 0; i < 4; ++i) a[i] = As[k][ty*4+i];
      #pragma unroll
      for (int j = 0; j < 4; ++j) b[j] = Bs[k][tx*4+j];
      #pragma unroll
      for (int i = 0; i < 4; ++i)
        #pragma unroll
        for (int j = 0; j < 4; ++j)
          acc[i][j] = fmaf(a[i], b[j], acc[i][j]);
    }
    __syncthreads();
  }
  #pragma unroll
  for (int i = 0; i < 4; ++i) {
    int m = bm + ty*4 + i;
    if (m < M)
      *(float4*)(out + (size_t)m*Nn + tx*4) =
          make_float4(acc[i][0], acc[i][1], acc[i][2], acc[i][3]);
  }
}

// ---------------- attention logits layer 1 ----------------
__global__ void k_lr1(const float* __restrict__ feat1, const float* __restrict__ al,
                      const float* __restrict__ ar, float* __restrict__ el,
                      float* __restrict__ er, int Nn) {
  int n = blockIdx.x;
  int t = threadIdx.x;
  int h = t >> 6, lane = t & 63;
  float f = feat1[(size_t)n*256 + t];
  float pl = f * al[t];
  float pr = f * ar[t];
  #pragma unroll
  for (int m = 32; m >= 1; m >>= 1) {
    pl += __shfl_xor(pl, m);
    pr += __shfl_xor(pr, m);
  }
  if (lane == 0) {
    el[n*4 + h] = pl;
    er[n*4 + h] = pr;
  }
}

// ---------------- attention logits layer 2 ----------------
__global__ void k_lr2(const float* __restrict__ feat2, const float* __restrict__ al,
                      const float* __restrict__ ar, float* __restrict__ el,
                      float* __restrict__ er, int Nn) {
  int v = blockIdx.x*4 + (threadIdx.x >> 6);
  int lane = threadIdx.x & 63;
  if (v >= Nn) return;
  float f = feat2[(size_t)v*64 + lane];
  float pl = f * al[lane];
  float pr = f * ar[lane];
  #pragma unroll
  for (int m = 32; m >= 1; m >>= 1) {
    pl += __shfl_xor(pl, m);
    pr += __shfl_xor(pr, m);
  }
  if (lane == 0) { el[v] = pl; er[v] = pr; }
}

// ---------------- layer-1 softmax + aggregate + bias + ELU -> h1 ----------------
// 1 block per dst node; wave h handles head h. Weights computed in parallel into
// LDS, serial loop is just {LDS broadcast + gather + fmaf}.
__global__ __launch_bounds__(256) void k_agg1(const float* __restrict__ feat1,
                      const float* __restrict__ el, const float* __restrict__ er,
                      const int* __restrict__ row_start, const int* __restrict__ csr_src,
                      const float* __restrict__ b1, float* __restrict__ h1, int Nn) {
  __shared__ float w_sm[4][128];
  __shared__ int   s_sm[4][128];
  int v = blockIdx.x;
  int h = threadIdx.x >> 6, lane = threadIdx.x & 63;
  int r0 = row_start[v], deg = row_start[v+1] - r0;
  float erv = er[v*4 + h];
  // pass 1: max (strided, parallel)
  float mx = -INFINITY;
  for (int i = lane; i < deg; i += 64) {
    int s = csr_src[r0+i];
    float e = LRELU(el[s*4 + h] + erv);
    mx = fmaxf(mx, e);
  }
  #pragma unroll
  for (int m = 32; m >= 1; m >>= 1) mx = fmaxf(mx, __shfl_xor(mx, m));
  // pass 2: sum (strided, parallel)
  float sm = 0.f;
  for (int i = lane; i < deg; i += 64) {
    int s = csr_src[r0+i];
    float e = LRELU(el[s*4 + h] + erv);
    sm += __expf(e - mx);
  }
  #pragma unroll
  for (int m = 32; m >= 1; m >>= 1) sm += __shfl_xor(sm, m);
  float inv = (deg > 0) ? 1.f/sm : 0.f;
  // pass 3: chunks of 128: parallel weight compute -> LDS, then serial fmaf
  float acc = 0.f;
  for (int c0 = 0; c0 < deg; c0 += 128) {
    int cnt = min(128, deg - c0);
    #pragma unroll
    for (int q = 0; q < 2; ++q) {
      int j = q*64 + lane;
      if (j < cnt) {
        int s = csr_src[r0 + c0 + j];
        float e = LRELU(el[s*4 + h] + erv);
        w_sm[h][j] = __expf(e - mx) * inv;
        s_sm[h][j] = s*256 + h*64;
      }
    }
    for (int j = 0; j < cnt; ++j) {
      acc = fmaf(feat1[(size_t)(s_sm[h][j] + lane)], w_sm[h][j], acc);
    }
  }
  float val = acc + b1[h*64 + lane];
  val = val > 0.f ? val : expm1f(val);
  h1[(size_t)v*256 + h*64 + lane] = val;
}

// ---------------- layer-2 softmax + aggregate + bias -> out ----------------
// wave per node (H=1, D=64), same chunked structure
__global__ __launch_bounds__(256) void k_agg2(const float* __restrict__ feat2,
                      const float* __restrict__ el, const float* __restrict__ er,
                      const int* __restrict__ row_start, const int* __restrict__ csr_src,
                      const float* __restrict__ b2, float* __restrict__ out, int Nn) {
  __shared__ float w_sm[4][64];
  __shared__ int   s_sm[4][64];
  int w = threadIdx.x >> 6;
  int v = blockIdx.x*4 + w;
  int lane = threadIdx.x & 63;
  if (v >= Nn) return;
  int r0 = row_start[v], deg = row_start[v+1] - r0;
  float erv = er[v];
  float mx = -INFINITY;
  for (int i = lane; i < deg; i += 64) {
    int s = csr_src[r0+i];
    float e = LRELU(el[s] + erv);
    mx = fmaxf(mx, e);
  }
  #pragma unroll
  for (int m = 32; m >= 1; m >>= 1) mx = fmaxf(mx, __shfl_xor(mx, m));
  float sm = 0.f;
  for (int i = lane; i < deg; i += 64) {
    int s = csr_src[r0+i];
    float e = LRELU(el[s] + erv);
    sm += __expf(e - mx);
  }
  #pragma unroll
  for (int m = 32; m >= 1; m >>= 1) sm += __shfl_xor(sm, m);
  float inv = (deg > 0) ? 1.f/sm : 0.f;
  float acc = 0.f;
  for (int c0 = 0; c0 < deg; c0 += 64) {
    int cnt = min(64, deg - c0);
    int j0 = lane;
    if (j0 < cnt) {
      int s = csr_src[r0 + c0 + j0];
      float e = LRELU(el[s] + erv);
      w_sm[w][j0] = __expf(e - mx) * inv;
      s_sm[w][j0] = s*64;
    }
    for (int j = 0; j < cnt; ++j) {
      acc = fmaf(feat2[(size_t)(s_sm[w][j] + lane)], w_sm[w][j], acc);
    }
  }
  out[(size_t)v*64 + lane] = acc + b2[lane];
}

extern "C" void kernel_launch(void* const* d_in, const int* in_sizes, int n_in,
                              void* d_out, int out_size, void* d_ws, size_t ws_size,
                              hipStream_t stream) {
  const float* x   = (const float*)d_in[0];
  const int*   src = (const int*)d_in[1];
  const int*   dst = (const int*)d_in[2];
  const float* W1  = (const float*)d_in[3];
  const float* al1 = (const float*)d_in[4];
  const float* ar1 = (const float*)d_in[5];
  const float* b1  = (const float*)d_in[6];
  const float* W2  = (const float*)d_in[7];
  const float* al2 = (const float*)d_in[8];
  const float* ar2 = (const float*)d_in[9];
  const float* b2  = (const float*)d_in[10];
  float* out = (float*)d_out;

  const int N = in_sizes[0] / 512;
  const int E = in_sizes[1];

  char* p = (char*)d_ws;
  auto alloc = [&](size_t bytes) {
    char* r = p; p += (bytes + 255) & ~(size_t)255; return r;
  };
  float* feat1    = (float*)alloc((size_t)N*256*sizeof(float));
  float* h1       = (float*)alloc((size_t)N*256*sizeof(float));
  float* feat2    = (float*)alloc((size_t)N*64*sizeof(float));
  float* el1      = (float*)alloc((size_t)N*4*sizeof(float));
  float* er1      = (float*)alloc((size_t)N*4*sizeof(float));
  float* el2      = (float*)alloc((size_t)N*sizeof(float));
  float* er2      = (float*)alloc((size_t)N*sizeof(float));
  int*   deg      = (int*)alloc((size_t)N*sizeof(int));
  int*   row_start= (int*)alloc((size_t)(N+1)*sizeof(int));
  int*   cursor   = (int*)alloc((size_t)N*sizeof(int));
  int*   bsums    = (int*)alloc(64*sizeof(int));
  int*   csr_src  = (int*)alloc((size_t)E*sizeof(int));
  __bf16* w1t     = (__bf16*)alloc((size_t)256*512*sizeof(__bf16));

  hipMemsetAsync(deg, 0, (size_t)N*sizeof(int), stream);
  hipMemsetAsync(cursor, 0, (size_t)N*sizeof(int), stream);

  k_hist<<<(E+255)/256, 256, 0, stream>>>(dst, deg, E);
  int nb = (N + 1023)/1024;
  k_scan1<<<nb, 1024, 0, stream>>>(deg, row_start, bsums, N);
  k_scan2<<<1, 64, 0, stream>>>(bsums, nb);
  k_scan3<<<nb, 1024, 0, stream>>>(row_start, bsums, N);
  k_fill<<<(E+255)/256, 256, 0, stream>>>(src, dst, row_start, cursor, csr_src, E);
  k_w1t<<<(256*512+255)/256, 256, 0, stream>>>(W1, w1t);

  k_gemm1<<<dim3((N+127)/128, 2), 256, 0, stream>>>(x, w1t, feat1, N);
  k_lr1<<<N, 256, 0, stream>>>(feat1, al1, ar1, el1, er1, N);
  k_agg1<<<N, 256, 0, stream>>>(feat1, el1, er1, row_start, csr_src, b1, h1, N);
  k_gemm2<<<(N+63)/64, 256, 0, stream>>>(h1, W2, feat2, N);
  k_lr2<<<(N+3)/4, 256, 0, stream>>>(feat2, al2, ar2, el2, er2, N);
  k_agg2<<<(N+3)/4, 256, 0, stream>>>(feat2, el2, er2, row_start, csr_src, b2, out, N);
}

// Round 6
// 328.801 us; speedup vs baseline: 2.0481x; 1.2492x over previous
//
#include <hip/hip_runtime.h>
#include <cmath>

#define LRELU(e) ((e) > 0.f ? (e) : 0.2f*(e))

typedef __bf16 bf16x8 __attribute__((ext_vector_type(8)));
typedef float  f32x4  __attribute__((ext_vector_type(4)));

// ---------------- CSR build ----------------
__global__ void k_hist(const int* __restrict__ dst, int* __restrict__ deg, int E) {
  int e = blockIdx.x*blockDim.x + threadIdx.x;
  if (e < E) atomicAdd(&deg[dst[e]], 1);
}

__global__ __launch_bounds__(1024) void k_scan1(const int* __restrict__ deg,
                        int* __restrict__ row_start, int* __restrict__ bsums, int n) {
  __shared__ int sm[1024];
  int t = threadIdx.x;
  int i = blockIdx.x*1024 + t;
  sm[t] = (i < n) ? deg[i] : 0;
  __syncthreads();
  for (int off = 1; off < 1024; off <<= 1) {
    int v = (t >= off) ? sm[t-off] : 0;
    __syncthreads();
    sm[t] += v;
    __syncthreads();
  }
  if (i < n) row_start[i+1] = sm[t];
  if (t == 1023) bsums[blockIdx.x] = sm[1023];
  if (i == 0) row_start[0] = 0;
}

__global__ void k_scan2(int* __restrict__ bsums, int nb) {
  __shared__ int sm[64];
  int t = threadIdx.x;
  sm[t] = (t < nb) ? bsums[t] : 0;
  __syncthreads();
  for (int off = 1; off < 64; off <<= 1) {
    int v = (t >= off) ? sm[t-off] : 0;
    __syncthreads();
    sm[t] += v;
    __syncthreads();
  }
  if (t < nb) bsums[t] = (t == 0) ? 0 : sm[t-1];
}

__global__ __launch_bounds__(1024) void k_scan3(int* __restrict__ row_start,
                        const int* __restrict__ bsums, int n) {
  int i = blockIdx.x*1024 + threadIdx.x;
  if (i < n) row_start[i+1] += bsums[blockIdx.x];
}

__global__ void k_fill(const int* __restrict__ src, const int* __restrict__ dst,
                       const int* __restrict__ row_start, int* __restrict__ cursor,
                       int* __restrict__ csr_src, int E) {
  int e = blockIdx.x*blockDim.x + threadIdx.x;
  if (e < E) {
    int d = dst[e];
    int pos = atomicAdd(&cursor[d], 1);
    csr_src[row_start[d] + pos] = src[e];
  }
}

// ---------------- weight transposes to bf16 ----------------
__global__ void k_w1t(const float* __restrict__ W1, __bf16* __restrict__ W1T) {
  int idx = blockIdx.x*blockDim.x + threadIdx.x;   // n*512 + k
  if (idx < 256*512) {
    int n = idx >> 9, k = idx & 511;
    W1T[idx] = (__bf16)W1[k*256 + n];
  }
}

__global__ void k_w2t(const float* __restrict__ W2, __bf16* __restrict__ W2T) {
  int idx = blockIdx.x*blockDim.x + threadIdx.x;   // n*256 + k
  if (idx < 64*256) {
    int n = idx >> 8, k = idx & 255;
    W2T[idx] = (__bf16)W2[k*64 + n];
  }
}

// ---------------- GEMM1 (bf16 MFMA) + fused lr1, bf16 feat1 out ----------------
// feat1[N,256] = x[N,512] @ W1[512,256]; el1/er1 from f32 accumulators.
// BM=128, BN=128, BK=32. 4 waves (2x2), wave tile 64x64 = one head (wn).
__global__ __launch_bounds__(256) void k_gemm1(const float* __restrict__ x,
                        const __bf16* __restrict__ W1T, __bf16* __restrict__ feat1,
                        const float* __restrict__ al1, const float* __restrict__ ar1,
                        float* __restrict__ el1, float* __restrict__ er1, int M) {
  const int K = 512, Nn = 256;
  __shared__ __bf16 A_sm[128][40];
  __shared__ __bf16 B_sm[128][40];
  int tid = threadIdx.x;
  int lane = tid & 63, wid = tid >> 6;
  int wm = wid >> 1, wn = wid & 1;
  int bm = blockIdx.x * 128;
  int bn = blockIdx.y * 128;
  int h = blockIdx.y * 2 + wn;

  int srow = tid >> 2;
  int scol = (tid & 3) * 8;

  f32x4 acc[4][4];
  #pragma unroll
  for (int i = 0; i < 4; ++i)
    #pragma unroll
    for (int j = 0; j < 4; ++j) acc[i][j] = (f32x4){0.f,0.f,0.f,0.f};

  for (int k0 = 0; k0 < K; k0 += 32) {
    #pragma unroll
    for (int p = 0; p < 2; ++p) {
      int row = srow + p*64;
      bf16x8 v;
      if (bm + row < M) {
        const float* xp = x + (size_t)(bm+row)*K + k0 + scol;
        float4 f0 = *(const float4*)xp;
        float4 f1 = *(const float4*)(xp+4);
        v[0]=(__bf16)f0.x; v[1]=(__bf16)f0.y; v[2]=(__bf16)f0.z; v[3]=(__bf16)f0.w;
        v[4]=(__bf16)f1.x; v[5]=(__bf16)f1.y; v[6]=(__bf16)f1.z; v[7]=(__bf16)f1.w;
      } else {
        v = (bf16x8){};
      }
      *(bf16x8*)&A_sm[row][scol] = v;
      *(bf16x8*)&B_sm[row][scol] = *(const bf16x8*)(W1T + (size_t)(bn+row)*K + k0 + scol);
    }
    __syncthreads();
    #pragma unroll
    for (int mf = 0; mf < 4; ++mf) {
      bf16x8 a = *(const bf16x8*)&A_sm[wm*64 + mf*16 + (lane&15)][(lane>>4)*8];
      #pragma unroll
      for (int nf = 0; nf < 4; ++nf) {
        bf16x8 b = *(const bf16x8*)&B_sm[wn*64 + nf*16 + (lane&15)][(lane>>4)*8];
        acc[mf][nf] = __builtin_amdgcn_mfma_f32_16x16x32_bf16(a, b, acc[mf][nf], 0, 0, 0);
      }
    }
    __syncthreads();
  }
  // per-lane attn weight slices for this head
  float al_r[4], ar_r[4];
  #pragma unroll
  for (int nf = 0; nf < 4; ++nf) {
    al_r[nf] = al1[h*64 + nf*16 + (lane&15)];
    ar_r[nf] = ar1[h*64 + nf*16 + (lane&15)];
  }
  #pragma unroll
  for (int mf = 0; mf < 4; ++mf) {
    #pragma unroll
    for (int j = 0; j < 4; ++j) {
      int m = bm + wm*64 + mf*16 + (lane>>4)*4 + j;
      float pl = 0.f, pr = 0.f;
      #pragma unroll
      for (int nf = 0; nf < 4; ++nf) {
        float val = acc[mf][nf][j];
        pl = fmaf(val, al_r[nf], pl);
        pr = fmaf(val, ar_r[nf], pr);
        if (m < M) {
          int n = bn + wn*64 + nf*16 + (lane&15);
          feat1[(size_t)m*Nn + n] = (__bf16)val;
        }
      }
      #pragma unroll
      for (int s = 8; s >= 1; s >>= 1) {
        pl += __shfl_xor(pl, s);
        pr += __shfl_xor(pr, s);
      }
      if ((lane & 15) == 0 && m < M) {
        el1[m*4 + h] = pl;
        er1[m*4 + h] = pr;
      }
    }
  }
}

// ---------------- GEMM2 (bf16 MFMA): feat2[N,64] = h1[N,256] @ W2[256,64] -----
// BM=128, BN=64, BK=32. 4 waves (2x2), wave tile 64x32.
__global__ __launch_bounds__(256) void k_gemm2(const __bf16* __restrict__ h1,
                        const __bf16* __restrict__ W2T, float* __restrict__ feat2, int M) {
  const int K = 256, Nn = 64;
  __shared__ __bf16 A_sm[128][40];
  __shared__ __bf16 B_sm[64][40];
  int tid = threadIdx.x;
  int lane = tid & 63, wid = tid >> 6;
  int wm = wid >> 1, wn = wid & 1;
  int bm = blockIdx.x * 128;

  int srow = tid >> 2;            // 0..63
  int scol = (tid & 3) * 8;

  f32x4 acc[4][2];
  #pragma unroll
  for (int i = 0; i < 4; ++i)
    #pragma unroll
    for (int j = 0; j < 2; ++j) acc[i][j] = (f32x4){0.f,0.f,0.f,0.f};

  for (int k0 = 0; k0 < K; k0 += 32) {
    #pragma unroll
    for (int p = 0; p < 2; ++p) {
      int row = p*64 + srow;
      bf16x8 v = (bf16x8){};
      if (bm + row < M) v = *(const bf16x8*)(h1 + (size_t)(bm+row)*K + k0 + scol);
      *(bf16x8*)&A_sm[row][scol] = v;
    }
    *(bf16x8*)&B_sm[srow][scol] = *(const bf16x8*)(W2T + (size_t)srow*K + k0 + scol);
    __syncthreads();
    #pragma unroll
    for (int mf = 0; mf < 4; ++mf) {
      bf16x8 a = *(const bf16x8*)&A_sm[wm*64 + mf*16 + (lane&15)][(lane>>4)*8];
      #pragma unroll
      for (int nf = 0; nf < 2; ++nf) {
        bf16x8 b = *(const bf16x8*)&B_sm[wn*32 + nf*16 + (lane&15)][(lane>>4)*8];
        acc[mf][nf] = __builtin_amdgcn_mfma_f32_16x16x32_bf16(a, b, acc[mf][nf], 0, 0, 0);
      }
    }
    __syncthreads();
  }
  #pragma unroll
  for (int mf = 0; mf < 4; ++mf) {
    #pragma unroll
    for (int j = 0; j < 4; ++j) {
      int m = bm + wm*64 + mf*16 + (lane>>4)*4 + j;
      if (m < M) {
        #pragma unroll
        for (int nf = 0; nf < 2; ++nf) {
          int n = wn*32 + nf*16 + (lane&15);
          feat2[(size_t)m*Nn + n] = acc[mf][nf][j];
        }
      }
    }
  }
}

// ---------------- attention logits layer 2 ----------------
__global__ void k_lr2(const float* __restrict__ feat2, const float* __restrict__ al,
                      const float* __restrict__ ar, float* __restrict__ el,
                      float* __restrict__ er, int Nn) {
  int v = blockIdx.x*4 + (threadIdx.x >> 6);
  int lane = threadIdx.x & 63;
  if (v >= Nn) return;
  float f = feat2[(size_t)v*64 + lane];
  float pl = f * al[lane];
  float pr = f * ar[lane];
  #pragma unroll
  for (int m = 32; m >= 1; m >>= 1) {
    pl += __shfl_xor(pl, m);
    pr += __shfl_xor(pr, m);
  }
  if (lane == 0) { el[v] = pl; er[v] = pr; }
}

// ---------------- layer-1 softmax + aggregate + bias + ELU -> h1 (bf16) -------
// 1 block per dst node; wave h handles head h. Single el-gather pass, no max
// (|e| is small; softmax is shift-invariant). exp values cached in LDS.
__global__ __launch_bounds__(256) void k_agg1(const __bf16* __restrict__ feat1,
                      const float* __restrict__ el, const float* __restrict__ er,
                      const int* __restrict__ row_start, const int* __restrict__ csr_src,
                      const float* __restrict__ b1, __bf16* __restrict__ h1, int Nn) {
  __shared__ float ex_sm[4][128];
  __shared__ int   s_sm[4][128];
  int v = blockIdx.x;
  int h = threadIdx.x >> 6, lane = threadIdx.x & 63;
  int r0 = row_start[v], deg = row_start[v+1] - r0;
  float erv = er[v*4 + h];
  float acc = 0.f;
  float inv = 0.f;
  if (deg <= 128) {
    float sm = 0.f;
    for (int i = lane; i < deg; i += 64) {
      int s = csr_src[r0+i];
      float e = LRELU(el[s*4 + h] + erv);
      float ex = __expf(e);
      ex_sm[h][i] = ex;
      s_sm[h][i] = s*256 + h*64;
      sm += ex;
    }
    #pragma unroll
    for (int m = 32; m >= 1; m >>= 1) sm += __shfl_xor(sm, m);
    inv = (deg > 0) ? 1.f/sm : 0.f;
    for (int j = 0; j < deg; ++j) {
      acc = fmaf((float)feat1[(size_t)(s_sm[h][j] + lane)], ex_sm[h][j], acc);
    }
  } else {
    float sm = 0.f;
    for (int i = lane; i < deg; i += 64) {
      int s = csr_src[r0+i];
      float e = LRELU(el[s*4 + h] + erv);
      sm += __expf(e);
    }
    #pragma unroll
    for (int m = 32; m >= 1; m >>= 1) sm += __shfl_xor(sm, m);
    inv = 1.f/sm;
    for (int c0 = 0; c0 < deg; c0 += 128) {
      int cnt = min(128, deg - c0);
      #pragma unroll
      for (int q = 0; q < 2; ++q) {
        int j = q*64 + lane;
        if (j < cnt) {
          int s = csr_src[r0 + c0 + j];
          float e = LRELU(el[s*4 + h] + erv);
          ex_sm[h][j] = __expf(e);
          s_sm[h][j] = s*256 + h*64;
        }
      }
      for (int j = 0; j < cnt; ++j) {
        acc = fmaf((float)feat1[(size_t)(s_sm[h][j] + lane)], ex_sm[h][j], acc);
      }
    }
  }
  float val = acc*inv + b1[h*64 + lane];
  val = val > 0.f ? val : expm1f(val);
  h1[(size_t)v*256 + h*64 + lane] = (__bf16)val;
}

// ---------------- layer-2 softmax + aggregate + bias -> out (f32) ------------
__global__ __launch_bounds__(256) void k_agg2(const float* __restrict__ feat2,
                      const float* __restrict__ el, const float* __restrict__ er,
                      const int* __restrict__ row_start, const int* __restrict__ csr_src,
                      const float* __restrict__ b2, float* __restrict__ out, int Nn) {
  __shared__ float ex_sm[4][128];
  __shared__ int   s_sm[4][128];
  int w = threadIdx.x >> 6;
  int v = blockIdx.x*4 + w;
  int lane = threadIdx.x & 63;
  if (v >= Nn) return;
  int r0 = row_start[v], deg = row_start[v+1] - r0;
  float erv = er[v];
  float acc = 0.f;
  float inv = 0.f;
  if (deg <= 128) {
    float sm = 0.f;
    for (int i = lane; i < deg; i += 64) {
      int s = csr_src[r0+i];
      float e = LRELU(el[s] + erv);
      float ex = __expf(e);
      ex_sm[w][i] = ex;
      s_sm[w][i] = s*64;
      sm += ex;
    }
    #pragma unroll
    for (int m = 32; m >= 1; m >>= 1) sm += __shfl_xor(sm, m);
    inv = (deg > 0) ? 1.f/sm : 0.f;
    for (int j = 0; j < deg; ++j) {
      acc = fmaf(feat2[(size_t)(s_sm[w][j] + lane)], ex_sm[w][j], acc);
    }
  } else {
    float sm = 0.f;
    for (int i = lane; i < deg; i += 64) {
      int s = csr_src[r0+i];
      float e = LRELU(el[s] + erv);
      sm += __expf(e);
    }
    #pragma unroll
    for (int m = 32; m >= 1; m >>= 1) sm += __shfl_xor(sm, m);
    inv = 1.f/sm;
    for (int c0 = 0; c0 < deg; c0 += 128) {
      int cnt = min(128, deg - c0);
      #pragma unroll
      for (int q = 0; q < 2; ++q) {
        int j = q*64 + lane;
        if (j < cnt) {
          int s = csr_src[r0 + c0 + j];
          float e = LRELU(el[s] + erv);
          ex_sm[w][j] = __expf(e);
          s_sm[w][j] = s*64;
        }
      }
      for (int j = 0; j < cnt; ++j) {
        acc = fmaf(feat2[(size_t)(s_sm[w][j] + lane)], ex_sm[w][j], acc);
      }
    }
  }
  out[(size_t)v*64 + lane] = acc*inv + b2[lane];
}

extern "C" void kernel_launch(void* const* d_in, const int* in_sizes, int n_in,
                              void* d_out, int out_size, void* d_ws, size_t ws_size,
                              hipStream_t stream) {
  const float* x   = (const float*)d_in[0];
  const int*   src = (const int*)d_in[1];
  const int*   dst = (const int*)d_in[2];
  const float* W1  = (const float*)d_in[3];
  const float* al1 = (const float*)d_in[4];
  const float* ar1 = (const float*)d_in[5];
  const float* b1  = (const float*)d_in[6];
  const float* W2  = (const float*)d_in[7];
  const float* al2 = (const float*)d_in[8];
  const float* ar2 = (const float*)d_in[9];
  const float* b2  = (const float*)d_in[10];
  float* out = (float*)d_out;

  const int N = in_sizes[0] / 512;
  const int E = in_sizes[1];

  char* p = (char*)d_ws;
  auto alloc = [&](size_t bytes) {
    char* r = p; p += (bytes + 255) & ~(size_t)255; return r;
  };
  __bf16* feat1   = (__bf16*)alloc((size_t)N*256*sizeof(__bf16));
  __bf16* h1      = (__bf16*)alloc((size_t)N*256*sizeof(__bf16));
  float* feat2    = (float*)alloc((size_t)N*64*sizeof(float));
  float* el1      = (float*)alloc((size_t)N*4*sizeof(float));
  float* er1      = (float*)alloc((size_t)N*4*sizeof(float));
  float* el2      = (float*)alloc((size_t)N*sizeof(float));
  float* er2      = (float*)alloc((size_t)N*sizeof(float));
  int*   deg      = (int*)alloc((size_t)N*sizeof(int));
  int*   row_start= (int*)alloc((size_t)(N+1)*sizeof(int));
  int*   cursor   = (int*)alloc((size_t)N*sizeof(int));
  int*   bsums    = (int*)alloc(64*sizeof(int));
  int*   csr_src  = (int*)alloc((size_t)E*sizeof(int));
  __bf16* w1t     = (__bf16*)alloc((size_t)256*512*sizeof(__bf16));
  __bf16* w2t     = (__bf16*)alloc((size_t)64*256*sizeof(__bf16));

  hipMemsetAsync(deg, 0, (size_t)N*sizeof(int), stream);
  hipMemsetAsync(cursor, 0, (size_t)N*sizeof(int), stream);

  k_hist<<<(E+255)/256, 256, 0, stream>>>(dst, deg, E);
  int nb = (N + 1023)/1024;
  k_scan1<<<nb, 1024, 0, stream>>>(deg, row_start, bsums, N);
  k_scan2<<<1, 64, 0, stream>>>(bsums, nb);
  k_scan3<<<nb, 1024, 0, stream>>>(row_start, bsums, N);
  k_fill<<<(E+255)/256, 256, 0, stream>>>(src, dst, row_start, cursor, csr_src, E);
  k_w1t<<<(256*512+255)/256, 256, 0, stream>>>(W1, w1t);
  k_w2t<<<(64*256+255)/256, 256, 0, stream>>>(W2, w2t);

  k_gemm1<<<dim3((N+127)/128, 2), 256, 0, stream>>>(x, w1t, feat1, al1, ar1, el1, er1, N);
  k_agg1<<<N, 256, 0, stream>>>(feat1, el1, er1, row_start, csr_src, b1, h1, N);
  k_gemm2<<<(N+127)/128, 256, 0, stream>>>(h1, w2t, feat2, N);
  k_lr2<<<(N+3)/4, 256, 0, stream>>>(feat2, al2, ar2, el2, er2, N);
  k_agg2<<<(N+3)/4, 256, 0, stream>>>(feat2, el2, er2, row_start, csr_src, b2, out, N);
}